// Round 18
// baseline (35.711 us; speedup 1.0000x reference)
//
#include <hip/hip_runtime.h>
#include <hip/hip_bf16.h>
#include <math.h>

// LinearAttention: X = Qf @ (Kf^T @ Vm) per (b,h); B=2 H=12 N=4096 D=64 fp32.
// Qf=(elu(Q)+1)*s ; Kf=(elu(K)+1)*m*s ; Vm=V*m ; s = 4096^-0.25 = 0.125.
//
// Champion (R17, 29.8us) + parallel pass1 epilogue: final combine/convert/store
// split across waves 0 AND 1 (was wave0-only), bit-identical math.
//  pass1: grid (24,16)x256; both 32-row chunks' loads hoisted (144 dwords/lane
//         in flight); bf16 fragment-native partial (8 KB/slab).
//  pass2: 16-slab bf16 reduce (fp32 accum) -> bf16 ktvT[e][d].
//  pass3: swapped operands, float4 C-writes.

#define BH_TOT 24
#define NROWS 4096
#define DD 64
#define SLABS 16

typedef __attribute__((ext_vector_type(8))) short bf16x8;   // 8 x bf16
typedef __attribute__((ext_vector_type(4))) float f32x4;    // MFMA C/D frag

__device__ __forceinline__ float elu1(float x) {
    return x > 0.0f ? x + 1.0f : __expf(x);
}
__device__ __forceinline__ short f2bf(float x) {
    __hip_bfloat16 h = __float2bfloat16(x);
    return *reinterpret_cast<short*>(&h);
}
__device__ __forceinline__ float bf2f(unsigned short u) {
    unsigned int v = (unsigned int)u << 16;
    return __builtin_bit_cast(float, v);
}

// ---------------- Pass 1: per-block partial KtV^T (fragment-native bf16) ----------------
// grid (24, 16), block 256 (4 waves); wave covers 2 x 32-row chunks (64 rows).
// Swapped MFMA: acc[je][id] = D[e-tile je][d-tile id]; e=16je+4g+r, d=16id+cl.
__global__ __launch_bounds__(256) void la_pass1(
        const float* __restrict__ K, const float* __restrict__ V,
        const float* __restrict__ mask, ushort4* __restrict__ partial,
        float scale) {
    const int bh   = blockIdx.x;
    const int slab = blockIdx.y;
    const int wave = threadIdx.x >> 6;
    const int lane = threadIdx.x & 63;
    const int g = lane >> 4, rg = g * 8, cl = lane & 15;

    const float* __restrict__ Kp = K + (size_t)bh * NROWS * DD;
    const float* __restrict__ Vp = V + (size_t)bh * NROWS * DD;
    const float* __restrict__ mp = mask + (size_t)(bh / 12) * NROWS;

    const int n0 = (slab * 4 + wave) * 64;

    // ---- issue ALL loads for both chunks first (144 dwords/lane in flight) ----
    float mrow[2][8], kr[2][8][4], vr[2][8][4];
#pragma unroll
    for (int c = 0; c < 2; ++c) {
        const int nb = n0 + c * 32 + rg;              // this lane's 8-row group
        const float* kb = Kp + (size_t)nb * DD + cl;
        const float* vb = Vp + (size_t)nb * DD + cl;
#pragma unroll
        for (int jj = 0; jj < 8; ++jj) {
            mrow[c][jj] = mp[nb + jj];
#pragma unroll
            for (int i = 0; i < 4; ++i) {
                kr[c][jj][i] = kb[jj * DD + i * 16];  // imm-offset dword loads
                vr[c][jj][i] = vb[jj * DD + i * 16];
            }
        }
    }

    f32x4 acc[4][4];   // [je][id]
#pragma unroll
    for (int je = 0; je < 4; ++je)
#pragma unroll
        for (int id = 0; id < 4; ++id) acc[je][id] = (f32x4)0.0f;

#pragma unroll
    for (int c = 0; c < 2; ++c) {
        bf16x8 af[4], bv[4];
#pragma unroll
        for (int i = 0; i < 4; ++i)
#pragma unroll
            for (int jj = 0; jj < 8; ++jj) {
                af[i][jj] = f2bf(elu1(kr[c][jj][i]) * (mrow[c][jj] * scale));
                bv[i][jj] = f2bf(vr[c][jj][i] * mrow[c][jj]);
            }
        // D[e][d] = sum_n Vm[n][e] * Kf[n][d]
#pragma unroll
        for (int je = 0; je < 4; ++je)
#pragma unroll
            for (int id = 0; id < 4; ++id)
                acc[je][id] = __builtin_amdgcn_mfma_f32_16x16x32_bf16(
                                  bv[je], af[id], acc[je][id], 0, 0, 0);
    }

    // ---- cross-wave reduce, fragment-native (all b128, conflict-free) ----
    // stage 1: w2,w3 publish; w0 += w2, w1 += w3.
    __shared__ f32x4 red[2][16][64];      // 32 KB
    if (wave >= 2) {
#pragma unroll
        for (int je = 0; je < 4; ++je)
#pragma unroll
            for (int id = 0; id < 4; ++id)
                red[wave - 2][je * 4 + id][lane] = acc[je][id];
    }
    __syncthreads();
    if (wave < 2) {
#pragma unroll
        for (int je = 0; je < 4; ++je)
#pragma unroll
            for (int id = 0; id < 4; ++id)
                acc[je][id] += red[wave][je * 4 + id][lane];
    }
    __syncthreads();
    // stage 2 (parallel finalize): w0 publishes je<2, w1 publishes je>=2;
    // then w1 finalizes tiles je<2, w0 finalizes je>=2. fp32 add is commutative
    // -> bit-identical to single-wave order.
    if (wave == 0) {
#pragma unroll
        for (int je = 0; je < 2; ++je)
#pragma unroll
            for (int id = 0; id < 4; ++id)
                red[0][je * 4 + id][lane] = acc[je][id];
    } else if (wave == 1) {
#pragma unroll
        for (int je = 2; je < 4; ++je)
#pragma unroll
            for (int id = 0; id < 4; ++id)
                red[0][je * 4 + id][lane] = acc[je][id];
    }
    __syncthreads();
    if (wave < 2) {
        ushort4* out = partial + ((size_t)bh * SLABS + slab) * 1024;
        const int je0 = (wave == 0) ? 2 : 0;   // w0 -> je 2,3 ; w1 -> je 0,1
#pragma unroll
        for (int jd = 0; jd < 2; ++jd) {
            const int je = je0 + jd;
#pragma unroll
            for (int id = 0; id < 4; ++id) {
                f32x4 v = acc[je][id] + red[0][je * 4 + id][lane];
                ushort4 u;
                u.x = (unsigned short)f2bf(v[0]); u.y = (unsigned short)f2bf(v[1]);
                u.z = (unsigned short)f2bf(v[2]); u.w = (unsigned short)f2bf(v[3]);
                out[(je * 4 + id) * 64 + lane] = u;
            }
        }
    }
}

// ---------------- Pass 2: reduce 16 bf16 slabs -> bf16 ktvT[e][d] ----------------
// grid (24, 4), block 256. One position per thread: pos in [0,1024).
// pos = frag*64 + ln ; frag = je*4+id ; e0 = 16*je + 4*(ln>>4) ; d = 16*id + (ln&15).
__global__ __launch_bounds__(256) void la_pass2(
        const ushort4* __restrict__ partial, __hip_bfloat16* __restrict__ ktvT) {
    const int bh  = blockIdx.x;
    const int pos = blockIdx.y * 256 + threadIdx.x;    // 0..1023
    const ushort4* base = partial + (size_t)bh * SLABS * 1024 + pos;
    float s0 = 0.f, s1 = 0.f, s2 = 0.f, s3 = 0.f;
#pragma unroll
    for (int w = 0; w < SLABS; ++w) {
        ushort4 u = base[(size_t)w * 1024];
        s0 += bf2f(u.x); s1 += bf2f(u.y); s2 += bf2f(u.z); s3 += bf2f(u.w);
    }
    const int frag = pos >> 6, ln = pos & 63;
    const int e0 = 16 * (frag >> 2) + 4 * (ln >> 4);
    const int d  = 16 * (frag & 3) + (ln & 15);
    __hip_bfloat16* ko = ktvT + (size_t)bh * DD * DD;
    ko[(size_t)(e0 + 0) * DD + d] = __float2bfloat16(s0);
    ko[(size_t)(e0 + 1) * DD + d] = __float2bfloat16(s1);
    ko[(size_t)(e0 + 2) * DD + d] = __float2bfloat16(s2);
    ko[(size_t)(e0 + 3) * DD + d] = __float2bfloat16(s3);
}

// ---------------- Pass 3: X = Qf @ KtV (swapped operands) ----------------
// grid (24, 32), block 256; wave handles 32 rows (t=0..1 n-tiles).
__global__ __launch_bounds__(256) void la_pass3(
        const float* __restrict__ Q, const __hip_bfloat16* __restrict__ ktvT,
        float* __restrict__ X, float scale) {
    const int bh   = blockIdx.x;
    const int wave = threadIdx.x >> 6;
    const int lane = threadIdx.x & 63;
    const int n0   = blockIdx.y * 128 + wave * 32;
    const int g = lane >> 4, rg = g * 8, cl = lane & 15;

    // A-frag(i,c2): A[row=16i+cl][k=32c2+rg+jj] = ktvT[16i+cl][32c2+rg+jj] (16B)
    bf16x8 afr[4][2];
#pragma unroll
    for (int i = 0; i < 4; ++i)
#pragma unroll
        for (int c2 = 0; c2 < 2; ++c2)
            afr[i][c2] = *reinterpret_cast<const bf16x8*>(
                ktvT + (size_t)bh * DD * DD + (size_t)(16 * i + cl) * DD + 32 * c2 + rg);

    // B-frag(t,c2): B[k=32c2+rg+jj][col=16t+cl] = Qf[n0+16t+cl][32c2+rg+jj]
    const float* Qp = Q + (size_t)bh * NROWS * DD;
    bf16x8 bfr[2][2];
#pragma unroll
    for (int t = 0; t < 2; ++t)
#pragma unroll
        for (int c2 = 0; c2 < 2; ++c2) {
            const float* qp = Qp + (size_t)(n0 + 16 * t + cl) * DD + 32 * c2 + rg;
            float4 q0 = ((const float4*)qp)[0];
            float4 q1 = ((const float4*)qp)[1];
            bf16x8 a;
            a[0] = f2bf(elu1(q0.x) * scale); a[1] = f2bf(elu1(q0.y) * scale);
            a[2] = f2bf(elu1(q0.z) * scale); a[3] = f2bf(elu1(q0.w) * scale);
            a[4] = f2bf(elu1(q1.x) * scale); a[5] = f2bf(elu1(q1.y) * scale);
            a[6] = f2bf(elu1(q1.z) * scale); a[7] = f2bf(elu1(q1.w) * scale);
            bfr[t][c2] = a;
        }

    f32x4 acc[4][2];
#pragma unroll
    for (int i = 0; i < 4; ++i)
#pragma unroll
        for (int t = 0; t < 2; ++t) acc[i][t] = (f32x4)0.0f;

#pragma unroll
    for (int i = 0; i < 4; ++i)
#pragma unroll
        for (int t = 0; t < 2; ++t) {
            acc[i][t] = __builtin_amdgcn_mfma_f32_16x16x32_bf16(
                            afr[i][0], bfr[t][0], acc[i][t], 0, 0, 0);
            acc[i][t] = __builtin_amdgcn_mfma_f32_16x16x32_bf16(
                            afr[i][1], bfr[t][1], acc[i][t], 0, 0, 0);
        }

    // store: X[n0+16t+cl][16i+4g .. +3] <- acc[i][t][0..3]  (float4)
    float* Xp = X + (size_t)bh * NROWS * DD;
#pragma unroll
    for (int i = 0; i < 4; ++i)
#pragma unroll
        for (int t = 0; t < 2; ++t) {
            float4 v = make_float4(acc[i][t][0], acc[i][t][1],
                                   acc[i][t][2], acc[i][t][3]);
            *reinterpret_cast<float4*>(
                Xp + (size_t)(n0 + 16 * t + cl) * DD + 16 * i + 4 * g) = v;
        }
}

extern "C" void kernel_launch(void* const* d_in, const int* in_sizes, int n_in,
                              void* d_out, int out_size, void* d_ws, size_t ws_size,
                              hipStream_t stream) {
    const float* Q    = (const float*)d_in[0];
    const float* K    = (const float*)d_in[1];
    const float* V    = (const float*)d_in[2];
    const float* mask = (const float*)d_in[3];
    float* X = (float*)d_out;

    const float scale = 0.125f;   // 4096^-0.25 exactly

    ushort4* partial = (ushort4*)d_ws;                    // 24*16*8KB = 3.15 MB
    __hip_bfloat16* ktvT =
        (__hip_bfloat16*)((char*)d_ws + (size_t)BH_TOT * SLABS * 1024 * 8);

    la_pass1<<<dim3(BH_TOT, SLABS), 256, 0, stream>>>(K, V, mask, partial, scale);
    la_pass2<<<dim3(BH_TOT, 4), 256, 0, stream>>>(partial, ktvT);
    la_pass3<<<dim3(BH_TOT, 32), 256, 0, stream>>>(Q, ktvT, X, scale);
}

// Round 19
// 29.749 us; speedup vs baseline: 1.2004x; 1.2004x over previous
//
#include <hip/hip_runtime.h>
#include <hip/hip_bf16.h>
#include <math.h>

// LinearAttention: X = Qf @ (Kf^T @ Vm) per (b,h); B=2 H=12 N=4096 D=64 fp32.
// Qf=(elu(Q)+1)*s ; Kf=(elu(K)+1)*m*s ; Vm=V*m ; s = 4096^-0.25 = 0.125.
//
// CHAMPION (R17, 29.8us): bf16 fragment-native partials.
//  pass1: grid (24,16)x256; both 32-row chunks' loads hoisted (144 dwords/lane
//         in flight); wave0 writes ushort4 bf16 partial (8 KB/slab).
//  pass2: 16-slab bf16 reduce (fp32 accum) -> bf16 ktvT[e][d].
//  pass3: swapped operands (ktvT as A) so C-writes are float4 stores.

#define BH_TOT 24
#define NROWS 4096
#define DD 64
#define SLABS 16

typedef __attribute__((ext_vector_type(8))) short bf16x8;   // 8 x bf16
typedef __attribute__((ext_vector_type(4))) float f32x4;    // MFMA C/D frag

__device__ __forceinline__ float elu1(float x) {
    return x > 0.0f ? x + 1.0f : __expf(x);
}
__device__ __forceinline__ short f2bf(float x) {
    __hip_bfloat16 h = __float2bfloat16(x);
    return *reinterpret_cast<short*>(&h);
}
__device__ __forceinline__ float bf2f(unsigned short u) {
    unsigned int v = (unsigned int)u << 16;
    return __builtin_bit_cast(float, v);
}

// ---------------- Pass 1: per-block partial KtV^T (fragment-native bf16) ----------------
// grid (24, 16), block 256 (4 waves); wave covers 2 x 32-row chunks (64 rows).
// Swapped MFMA: acc[je][id] = D[e-tile je][d-tile id]; e=16je+4g+r, d=16id+cl.
__global__ __launch_bounds__(256) void la_pass1(
        const float* __restrict__ K, const float* __restrict__ V,
        const float* __restrict__ mask, ushort4* __restrict__ partial,
        float scale) {
    const int bh   = blockIdx.x;
    const int slab = blockIdx.y;
    const int wave = threadIdx.x >> 6;
    const int lane = threadIdx.x & 63;
    const int g = lane >> 4, rg = g * 8, cl = lane & 15;

    const float* __restrict__ Kp = K + (size_t)bh * NROWS * DD;
    const float* __restrict__ Vp = V + (size_t)bh * NROWS * DD;
    const float* __restrict__ mp = mask + (size_t)(bh / 12) * NROWS;

    const int n0 = (slab * 4 + wave) * 64;

    // ---- issue ALL loads for both chunks first (144 dwords/lane in flight) ----
    float mrow[2][8], kr[2][8][4], vr[2][8][4];
#pragma unroll
    for (int c = 0; c < 2; ++c) {
        const int nb = n0 + c * 32 + rg;              // this lane's 8-row group
        const float* kb = Kp + (size_t)nb * DD + cl;
        const float* vb = Vp + (size_t)nb * DD + cl;
#pragma unroll
        for (int jj = 0; jj < 8; ++jj) {
            mrow[c][jj] = mp[nb + jj];
#pragma unroll
            for (int i = 0; i < 4; ++i) {
                kr[c][jj][i] = kb[jj * DD + i * 16];  // imm-offset dword loads
                vr[c][jj][i] = vb[jj * DD + i * 16];
            }
        }
    }

    f32x4 acc[4][4];   // [je][id]
#pragma unroll
    for (int je = 0; je < 4; ++je)
#pragma unroll
        for (int id = 0; id < 4; ++id) acc[je][id] = (f32x4)0.0f;

#pragma unroll
    for (int c = 0; c < 2; ++c) {
        bf16x8 af[4], bv[4];
#pragma unroll
        for (int i = 0; i < 4; ++i)
#pragma unroll
            for (int jj = 0; jj < 8; ++jj) {
                af[i][jj] = f2bf(elu1(kr[c][jj][i]) * (mrow[c][jj] * scale));
                bv[i][jj] = f2bf(vr[c][jj][i] * mrow[c][jj]);
            }
        // D[e][d] = sum_n Vm[n][e] * Kf[n][d]
#pragma unroll
        for (int je = 0; je < 4; ++je)
#pragma unroll
            for (int id = 0; id < 4; ++id)
                acc[je][id] = __builtin_amdgcn_mfma_f32_16x16x32_bf16(
                                  bv[je], af[id], acc[je][id], 0, 0, 0);
    }

    // ---- cross-wave reduce, fragment-native (all b128, conflict-free) ----
    __shared__ f32x4 red[2][16][64];      // 32 KB
    if (wave >= 2) {
#pragma unroll
        for (int je = 0; je < 4; ++je)
#pragma unroll
            for (int id = 0; id < 4; ++id)
                red[wave - 2][je * 4 + id][lane] = acc[je][id];
    }
    __syncthreads();
    if (wave < 2) {
#pragma unroll
        for (int je = 0; je < 4; ++je)
#pragma unroll
            for (int id = 0; id < 4; ++id)
                acc[je][id] += red[wave][je * 4 + id][lane];
    }
    __syncthreads();
    if (wave == 1) {
#pragma unroll
        for (int je = 0; je < 4; ++je)
#pragma unroll
            for (int id = 0; id < 4; ++id)
                red[0][je * 4 + id][lane] = acc[je][id];
    }
    __syncthreads();
    if (wave == 0) {
        ushort4* out = partial + ((size_t)bh * SLABS + slab) * 1024;
#pragma unroll
        for (int je = 0; je < 4; ++je)
#pragma unroll
            for (int id = 0; id < 4; ++id) {
                f32x4 v = acc[je][id] + red[0][je * 4 + id][lane];
                ushort4 u;
                u.x = (unsigned short)f2bf(v[0]); u.y = (unsigned short)f2bf(v[1]);
                u.z = (unsigned short)f2bf(v[2]); u.w = (unsigned short)f2bf(v[3]);
                out[(je * 4 + id) * 64 + lane] = u;
            }
    }
}

// ---------------- Pass 2: reduce 16 bf16 slabs -> bf16 ktvT[e][d] ----------------
// grid (24, 4), block 256. One position per thread: pos in [0,1024).
// pos = frag*64 + ln ; frag = je*4+id ; e0 = 16*je + 4*(ln>>4) ; d = 16*id + (ln&15).
__global__ __launch_bounds__(256) void la_pass2(
        const ushort4* __restrict__ partial, __hip_bfloat16* __restrict__ ktvT) {
    const int bh  = blockIdx.x;
    const int pos = blockIdx.y * 256 + threadIdx.x;    // 0..1023
    const ushort4* base = partial + (size_t)bh * SLABS * 1024 + pos;
    float s0 = 0.f, s1 = 0.f, s2 = 0.f, s3 = 0.f;
#pragma unroll
    for (int w = 0; w < SLABS; ++w) {
        ushort4 u = base[(size_t)w * 1024];
        s0 += bf2f(u.x); s1 += bf2f(u.y); s2 += bf2f(u.z); s3 += bf2f(u.w);
    }
    const int frag = pos >> 6, ln = pos & 63;
    const int e0 = 16 * (frag >> 2) + 4 * (ln >> 4);
    const int d  = 16 * (frag & 3) + (ln & 15);
    __hip_bfloat16* ko = ktvT + (size_t)bh * DD * DD;
    ko[(size_t)(e0 + 0) * DD + d] = __float2bfloat16(s0);
    ko[(size_t)(e0 + 1) * DD + d] = __float2bfloat16(s1);
    ko[(size_t)(e0 + 2) * DD + d] = __float2bfloat16(s2);
    ko[(size_t)(e0 + 3) * DD + d] = __float2bfloat16(s3);
}

// ---------------- Pass 3: X = Qf @ KtV (swapped operands) ----------------
// grid (24, 32), block 256; wave handles 32 rows (t=0..1 n-tiles).
__global__ __launch_bounds__(256) void la_pass3(
        const float* __restrict__ Q, const __hip_bfloat16* __restrict__ ktvT,
        float* __restrict__ X, float scale) {
    const int bh   = blockIdx.x;
    const int wave = threadIdx.x >> 6;
    const int lane = threadIdx.x & 63;
    const int n0   = blockIdx.y * 128 + wave * 32;
    const int g = lane >> 4, rg = g * 8, cl = lane & 15;

    // A-frag(i,c2): A[row=16i+cl][k=32c2+rg+jj] = ktvT[16i+cl][32c2+rg+jj] (16B)
    bf16x8 afr[4][2];
#pragma unroll
    for (int i = 0; i < 4; ++i)
#pragma unroll
        for (int c2 = 0; c2 < 2; ++c2)
            afr[i][c2] = *reinterpret_cast<const bf16x8*>(
                ktvT + (size_t)bh * DD * DD + (size_t)(16 * i + cl) * DD + 32 * c2 + rg);

    // B-frag(t,c2): B[k=32c2+rg+jj][col=16t+cl] = Qf[n0+16t+cl][32c2+rg+jj]
    const float* Qp = Q + (size_t)bh * NROWS * DD;
    bf16x8 bfr[2][2];
#pragma unroll
    for (int t = 0; t < 2; ++t)
#pragma unroll
        for (int c2 = 0; c2 < 2; ++c2) {
            const float* qp = Qp + (size_t)(n0 + 16 * t + cl) * DD + 32 * c2 + rg;
            float4 q0 = ((const float4*)qp)[0];
            float4 q1 = ((const float4*)qp)[1];
            bf16x8 a;
            a[0] = f2bf(elu1(q0.x) * scale); a[1] = f2bf(elu1(q0.y) * scale);
            a[2] = f2bf(elu1(q0.z) * scale); a[3] = f2bf(elu1(q0.w) * scale);
            a[4] = f2bf(elu1(q1.x) * scale); a[5] = f2bf(elu1(q1.y) * scale);
            a[6] = f2bf(elu1(q1.z) * scale); a[7] = f2bf(elu1(q1.w) * scale);
            bfr[t][c2] = a;
        }

    f32x4 acc[4][2];
#pragma unroll
    for (int i = 0; i < 4; ++i)
#pragma unroll
        for (int t = 0; t < 2; ++t) acc[i][t] = (f32x4)0.0f;

#pragma unroll
    for (int i = 0; i < 4; ++i)
#pragma unroll
        for (int t = 0; t < 2; ++t) {
            acc[i][t] = __builtin_amdgcn_mfma_f32_16x16x32_bf16(
                            afr[i][0], bfr[t][0], acc[i][t], 0, 0, 0);
            acc[i][t] = __builtin_amdgcn_mfma_f32_16x16x32_bf16(
                            afr[i][1], bfr[t][1], acc[i][t], 0, 0, 0);
        }

    // store: X[n0+16t+cl][16i+4g .. +3] <- acc[i][t][0..3]  (float4)
    float* Xp = X + (size_t)bh * NROWS * DD;
#pragma unroll
    for (int i = 0; i < 4; ++i)
#pragma unroll
        for (int t = 0; t < 2; ++t) {
            float4 v = make_float4(acc[i][t][0], acc[i][t][1],
                                   acc[i][t][2], acc[i][t][3]);
            *reinterpret_cast<float4*>(
                Xp + (size_t)(n0 + 16 * t + cl) * DD + 16 * i + 4 * g) = v;
        }
}

extern "C" void kernel_launch(void* const* d_in, const int* in_sizes, int n_in,
                              void* d_out, int out_size, void* d_ws, size_t ws_size,
                              hipStream_t stream) {
    const float* Q    = (const float*)d_in[0];
    const float* K    = (const float*)d_in[1];
    const float* V    = (const float*)d_in[2];
    const float* mask = (const float*)d_in[3];
    float* X = (float*)d_out;

    const float scale = 0.125f;   // 4096^-0.25 exactly

    ushort4* partial = (ushort4*)d_ws;                    // 24*16*8KB = 3.15 MB
    __hip_bfloat16* ktvT =
        (__hip_bfloat16*)((char*)d_ws + (size_t)BH_TOT * SLABS * 1024 * 8);

    la_pass1<<<dim3(BH_TOT, SLABS), 256, 0, stream>>>(K, V, mask, partial, scale);
    la_pass2<<<dim3(BH_TOT, 4), 256, 0, stream>>>(partial, ktvT);
    la_pass3<<<dim3(BH_TOT, 32), 256, 0, stream>>>(Q, ktvT, X, scale);
}